// Round 16
// baseline (2367.612 us; speedup 1.0000x reference)
//
#include <hip/hip_runtime.h>

#define Bq   1024
#define NQS  15
#define NCS  18
#define NMSS 20
#define NN   36864
#define DD   128
#define NTD  16
#define NP   5
#define NT   3

typedef __attribute__((ext_vector_type(8))) short short8;
typedef __attribute__((ext_vector_type(4))) short short4v;
typedef __attribute__((ext_vector_type(4))) float float4v;

__device__ __forceinline__ short f2bf(float f) {
  unsigned u = __builtin_bit_cast(unsigned, f);
  u = u + 0x7FFFu + ((u >> 16) & 1u);
  return (short)(u >> 16);
}
__device__ __forceinline__ float bf2f(short s) {
  unsigned u = ((unsigned)(unsigned short)s) << 16;
  return __builtin_bit_cast(float, u);
}

// HS / stgS: stride 256 shorts + XOR swizzle
__device__ __forceinline__ int hs_idx(int row, int col) {
  return (row << 8) + ((((col >> 3) ^ (row & 7)) << 3) | (col & 7));
}
// aggS: stride 128 + XOR swizzle
__device__ __forceinline__ int ag_idx(int row, int col) {
  return (row << 7) + ((((col >> 3) ^ (row & 7)) << 3) | (col & 7));
}
// actS: stride 136, unswizzled
#define ACT_STRIDE 136
__device__ __forceinline__ int as_idx(int row, int col) {
  return row * ACT_STRIDE + col;
}
// msgS: [128 feat][72 edge-slots]
#define MS_STRIDE 72
__device__ __forceinline__ int ms_idx(int f, int e) { return f * MS_STRIDE + e; }

// LDS layout (63552 B -> 2 blocks/CU)
#define OFF_ACT 24576
#define OFF_AGG 34368
#define OFF_UNI 43584
#define OFF_FR  62016
#define OFF_TO  62528
#define OFF_EF  63040
// t-phase overlays inside HS region:
#define TO_WT1  0
#define TO_WT2  8192
#define TO_MQ   9216
#define TO_MC   10496
#define TO_LA   11776
#define TO_RED  13376
#define TO_H1   13392

struct MP {
  const float* node_f; const float* edge_f;
  const int* from_idx; const int* to_idx;
  const short *WTc1, *WTm1, *WTu1, *WTc2, *WTm2, *WTu2;  // [M][256] bf16
  const float *b_c1, *b_c2, *b_m1, *b_m2, *b_u1, *b_u2;
  const float *c_n, *d_n, *c_e, *d_e;                     // folded fp32 constants [256]
  const float *W_t1, *b_t1, *W_t2, *b_t2;
  short* blkg;   // [NN][640] bf16
  short* mixg;   // [NN][512] bf16
  float* out;
};

// K=256 GEMM, 3 n-tiles (48 cols), full A preload.
template<int MT, typename F>
__device__ __forceinline__ void gemm3(const short* __restrict__ WT, F loadB,
                                      int wm, int quad, int l16, float4v (&acc)[MT][3]) {
  short8 afr[MT][8];
#pragma unroll
  for (int ks = 0; ks < 8; ++ks)
#pragma unroll
    for (int mt = 0; mt < MT; ++mt)
      afr[mt][ks] = *(const short8*)(WT + (long)(wm * (MT * 16) + mt * 16 + l16) * 256
                                        + ks * 32 + quad * 8);
#pragma unroll
  for (int mt = 0; mt < MT; ++mt)
#pragma unroll
    for (int nt = 0; nt < 3; ++nt) acc[mt][nt] = (float4v)0.f;
#pragma unroll
  for (int ks = 0; ks < 8; ++ks) {
    const int k0q = ks * 32 + quad * 8;
    short8 bfr[3];
#pragma unroll
    for (int nt = 0; nt < 3; ++nt) bfr[nt] = loadB(nt, k0q);
#pragma unroll
    for (int mt = 0; mt < MT; ++mt)
#pragma unroll
      for (int nt = 0; nt < 3; ++nt)
        acc[mt][nt] = __builtin_amdgcn_mfma_f32_16x16x32_bf16(afr[mt][ks], bfr[nt], acc[mt][nt], 0, 0, 0);
  }
}

// 1 batch / block, 512 threads, ~64KB LDS -> 2 independent barrier domains per CU.
// Final allocator spelling table (this toolchain, 512-thr blocks):
//   bare (512)            -> targets 128 regs (R11), no scheduler cap  <-- use this
//   waves_per_eu(2,2)     -> 128 regs but HARD-CAPS occupancy at 8 waves/CU (R15)
//   waves_per_eu(4)/(4,4) -> 64 regs + spills (R13/R14)
// Demand here is ~110 regs -> fits 128 spill-free; 64KB LDS + 128 regs lets the
// HW schedule 2 blocks/CU (16 waves) with independent barrier schedules.
__global__ __launch_bounds__(512)
void mega(MP P) {
  __shared__ __attribute__((aligned(16))) char smem[63552];
  short* HS   = (short*)smem;               // [48][256] bf16
  short* actS = (short*)(smem + OFF_ACT);
  short* aggS = (short*)(smem + OFF_AGG);
  short* stgS = (short*)(smem + OFF_UNI);   // staged comb-B [36][256]
  short* msgS = stgS;                       // [128][72] (aliased)
  float* xsT  = (float*)(smem + OFF_UNI);   // [33][132] fp32 (aliased, p==5/t-phase)
  int*   frS  = (int*)(smem + OFF_FR);
  int*   toS  = (int*)(smem + OFF_TO);
  float* efS  = (float*)(smem + OFF_EF);
  float* wt1S = (float*)(smem + TO_WT1);
  float* wt2S = (float*)(smem + TO_WT2);
  float* mqS  = (float*)(smem + TO_MQ);
  float* mcS  = (float*)(smem + TO_MC);
  float* laS  = (float*)(smem + TO_LA);
  float* redS = (float*)(smem + TO_RED);
  float* h1S  = (float*)(smem + TO_H1);

  const int tid = threadIdx.x, lane = tid & 63, wm = tid >> 6;  // wm 0..7
  const int quad = lane >> 4, l16 = lane & 15;
  const int b = blockIdx.x;           // batch
  const long nb = (long)b * 36;

  // edge topology (t-invariant): 90 active edges, padded to 128 with to=-1
  for (int j = tid; j < 128; j += 512) {
    if (j < 90) {
      int e = b * 135 + j;
      frS[j] = P.from_idx[e] - (int)nb;
      toS[j] = P.to_idx[e] - (int)nb;
      efS[j] = P.edge_f[e];
    } else { frS[j] = 0; toS[j] = -1; efS[j] = 0.f; }
  }
  __syncthreads();

  for (int t = 0; t < NT; ++t) {
    for (int p_ = (t == 0 ? 1 : 2); p_ <= NP; ++p_) {
      // ========== comb L1 -> HS ==========
      if (p_ == 1) {
        for (int i = tid; i < 48 * 256; i += 512) {
          int node = i >> 8, h = i & 255;
          int nc = node < 36 ? node : 35;
          float nf = P.node_f[nb + nc];
          float v = nf * P.c_n[h] + P.d_n[h] + P.b_c1[h];
          HS[hs_idx(node, h)] = f2bf(v > 0.f ? v : 0.f);
        }
      } else {
        float4v acc[2][3];
        gemm3<2>(P.WTc1, [&](int nt, int k0q) -> short8 {
          int n = nt * 16 + l16; int nc = n < 36 ? n : 35;
          return *(const short8*)(&stgS[hs_idx(nc, k0q)]);
        }, wm, quad, l16, acc);
#pragma unroll
        for (int mt = 0; mt < 2; ++mt) {
          const int h0 = wm * 32 + mt * 16 + quad * 4;
          float4v bv = *(const float4v*)(P.b_c1 + h0);
#pragma unroll
          for (int nt = 0; nt < 3; ++nt) {
            const int col = nt * 16 + l16;
            short4v hv;
#pragma unroll
            for (int r = 0; r < 4; ++r) {
              float v = acc[mt][nt][r] + bv[r];
              hv[r] = f2bf(v > 0.f ? v : 0.f);
            }
            *(short4v*)(&HS[hs_idx(col, h0)]) = hv;
          }
        }
      }
      __syncthreads();
      // ========== comb L2 -> actS ==========
      {
        float4v acc2[1][3];
        gemm3<1>(P.WTc2, [&](int nt, int k0q) -> short8 {
          return *(const short8*)(&HS[hs_idx(nt * 16 + l16, k0q)]);
        }, wm, quad, l16, acc2);
        const int f0 = wm * 16 + quad * 4;
        float4v bv = *(const float4v*)(P.b_c2 + f0);
#pragma unroll
        for (int nt = 0; nt < 3; ++nt) {
          int node = nt * 16 + l16;
          if (node < 36) {
            short4v ov;
#pragma unroll
            for (int r = 0; r < 4; ++r) ov[r] = f2bf(acc2[0][nt][r] + bv[r]);
            *(short4v*)(&actS[as_idx(node, f0)]) = ov;
          }
        }
      }
      __syncthreads();
      // ========== msg: 2 chunks of 48 edges ==========
      for (int c2 = 0; c2 < 2; ++c2) {
        // msg L1 -> HS
        {
          int fa[3], ta[3]; float ev[3];
#pragma unroll
          for (int nt = 0; nt < 3; ++nt) {
            int j = c2 * 48 + nt * 16 + l16;
            int fv = frS[j]; fa[nt] = fv < 0 ? 0 : fv;
            int tv = toS[j]; ta[nt] = tv < 0 ? 0 : tv;
            ev[nt] = efS[j];
          }
          float4v acc[2][3];
          gemm3<2>(P.WTm1, [&](int nt, int k0q) -> short8 {
            return (k0q < 128) ? *(const short8*)(&actS[as_idx(fa[nt], k0q)])
                               : *(const short8*)(&actS[as_idx(ta[nt], k0q - 128)]);
          }, wm, quad, l16, acc);
#pragma unroll
          for (int mt = 0; mt < 2; ++mt) {
            const int h0 = wm * 32 + mt * 16 + quad * 4;
            float4v bv = *(const float4v*)(P.b_m1 + h0);
            float4v ce = *(const float4v*)(P.c_e + h0);
            float4v de = *(const float4v*)(P.d_e + h0);
#pragma unroll
            for (int nt = 0; nt < 3; ++nt) {
              const int col = nt * 16 + l16;
              short4v hv;
#pragma unroll
              for (int r = 0; r < 4; ++r) {
                float v = acc[mt][nt][r] + bv[r] + de[r] + ev[nt] * ce[r];
                hv[r] = f2bf(v > 0.f ? v : 0.f);
              }
              *(short4v*)(&HS[hs_idx(col, h0)]) = hv;
            }
          }
        }
        __syncthreads();
        // msg L2 -> msgS
        {
          float4v acc2[1][3];
          gemm3<1>(P.WTm2, [&](int nt, int k0q) -> short8 {
            return *(const short8*)(&HS[hs_idx(nt * 16 + l16, k0q)]);
          }, wm, quad, l16, acc2);
          const int f0 = wm * 16 + quad * 4;
          float4v bv = *(const float4v*)(P.b_m2 + f0);
#pragma unroll
          for (int nt = 0; nt < 3; ++nt) {
            int e = nt * 16 + l16;
#pragma unroll
            for (int r = 0; r < 4; ++r)
              msgS[ms_idx(f0 + r, e)] = f2bf(acc2[0][nt][r] + bv[r]);
          }
        }
        __syncthreads();
        // agg chunk c2: aggS[node][f] (+)= Adj-select over 48 edges (K padded to 64)
        {
          float4v ag[3];
#pragma unroll
          for (int nt = 0; nt < 3; ++nt) ag[nt] = (float4v)0.f;
          const short ONE = (short)0x3F80;
#pragma unroll
          for (int ks = 0; ks < 2; ++ks) {
            const int k0 = ks * 32 + quad * 8;
            short8 a0 = *(const short8*)(&msgS[ms_idx(wm * 16 + l16, k0)]);
            int tv[8];
#pragma unroll
            for (int j = 0; j < 8; ++j) {
              int kk = k0 + j;
              tv[j] = (kk < 48) ? toS[c2 * 48 + kk] : -1;  // mask pad slots 48..63
            }
#pragma unroll
            for (int nt = 0; nt < 3; ++nt) {
              const int node = nt * 16 + l16;
              short8 bfr;
#pragma unroll
              for (int j = 0; j < 8; ++j) bfr[j] = (tv[j] == node) ? ONE : (short)0;
              ag[nt] = __builtin_amdgcn_mfma_f32_16x16x32_bf16(a0, bfr, ag[nt], 0, 0, 0);
            }
          }
          const int f0 = wm * 16 + quad * 4;
#pragma unroll
          for (int nt = 0; nt < 3; ++nt) {
            int node = nt * 16 + l16;
            if (node < 36) {
              if (c2 == 0) {
                short4v o2;
#pragma unroll
                for (int r = 0; r < 4; ++r) o2[r] = f2bf(ag[nt][r]);
                *(short4v*)(&aggS[ag_idx(node, f0)]) = o2;
              } else {
                short4v prev = *(short4v*)(&aggS[ag_idx(node, f0)]);
                short4v o2;
#pragma unroll
                for (int r = 0; r < 4; ++r) o2[r] = f2bf(bf2f(prev[r]) + ag[nt][r]);
                *(short4v*)(&aggS[ag_idx(node, f0)]) = o2;
              }
            }
          }
        }
        __syncthreads();
      }
      // ========== upd L1 -> HS (+ stage mixg half for next p) ==========
      {
        if (p_ < 5) {
          for (int i = tid; i < 36 * 16; i += 512) {
            int row = i >> 4, col = (i & 15) << 3;
            short8 v = *(const short8*)(P.mixg + (nb + row) * 512 + (p_ - 1) * 128 + col);
            *(short8*)(&stgS[hs_idx(row, 128 + col)]) = v;
          }
        }
        float4v acc[2][3];
        gemm3<2>(P.WTu1, [&](int nt, int k0q) -> short8 {
          int n = nt * 16 + l16; int nc = n < 36 ? n : 35;
          return (k0q < 128) ? *(const short8*)(&actS[as_idx(nc, k0q)])
                             : *(const short8*)(&aggS[ag_idx(nc, k0q - 128)]);
        }, wm, quad, l16, acc);
#pragma unroll
        for (int mt = 0; mt < 2; ++mt) {
          const int h0 = wm * 32 + mt * 16 + quad * 4;
          float4v bv = *(const float4v*)(P.b_u1 + h0);
#pragma unroll
          for (int nt = 0; nt < 3; ++nt) {
            const int col = nt * 16 + l16;
            short4v hv;
#pragma unroll
            for (int r = 0; r < 4; ++r) {
              float v = acc[mt][nt][r] + bv[r];
              hv[r] = f2bf(v > 0.f ? v : 0.f);
            }
            *(short4v*)(&HS[hs_idx(col, h0)]) = hv;
          }
        }
      }
      __syncthreads();
      // ========== upd L2 -> blkg(NT)+stgS (p<5) or xsT fp32 (p==5) ==========
      {
        float4v acc2[1][3];
        gemm3<1>(P.WTu2, [&](int nt, int k0q) -> short8 {
          return *(const short8*)(&HS[hs_idx(nt * 16 + l16, k0q)]);
        }, wm, quad, l16, acc2);
        const int f0 = wm * 16 + quad * 4;
        float4v bv = *(const float4v*)(P.b_u2 + f0);
#pragma unroll
        for (int nt = 0; nt < 3; ++nt) {
          int node = nt * 16 + l16;
          if (node < 36) {
            if (p_ < 5) {
              short4v ov;
#pragma unroll
              for (int r = 0; r < 4; ++r) ov[r] = f2bf(acc2[0][nt][r] + bv[r]);
              __builtin_nontemporal_store(ov, (short4v*)(P.blkg + (nb + node) * 640 + (p_ - 1) * 128 + f0));
              *(short4v*)(&stgS[hs_idx(node, f0)]) = ov;
            } else {
              if (node < 15 || node >= 18) {
                int row = (node < 15) ? node : node - 3;
                float4v xv;
#pragma unroll
                for (int r = 0; r < 4; ++r) xv[r] = acc2[0][nt][r] + bv[r];
                *(float4v*)(&xsT[row * 132 + f0]) = xv;
              }
            }
          }
        }
      }
      __syncthreads();
    }  // p loop

    // ================= t-phase (1 batch) =================
    for (int i = tid; i < 2048; i += 512) wt1S[i] = P.W_t1[i];
    if (tid < 256) wt2S[tid] = P.W_t2[tid];
    for (int i = tid; i < NMSS * NTD; i += 512) {
      int r = i >> 4;
      if (r >= NQS) mqS[i] = 0.f;
      if (r >= NCS) mcS[i] = 0.f;
    }
    __syncthreads();
    for (int i = tid; i < 33 * NTD; i += 512) {
      int r = i / NTD, c = i % NTD;
      float s = P.b_t1[c];
      for (int k = 0; k < 128; ++k) s += xsT[r * 132 + k] * wt1S[k * NTD + c];
      h1S[i] = s > 0.f ? s : 0.f;
    }
    __syncthreads();
    for (int i = tid; i < 33 * NTD; i += 512) {
      int r = i / NTD, c = i % NTD;
      float s = P.b_t2[c];
      for (int k = 0; k < NTD; ++k) s += h1S[r * NTD + k] * wt2S[k * NTD + c];
      if (r < NQS) mqS[r * NTD + c] = s;
      else         mcS[(r - NQS) * NTD + c] = s;
    }
    __syncthreads();
    for (int i = tid; i < 400; i += 512) {
      int q = i / 20, c = i - q * 20;
      float s = 0.f;
      for (int k = 0; k < NTD; ++k) s += mqS[q * NTD + k] * mcS[c * NTD + k];
      laS[i] = s * 10.f;  // / SINKHORN_TEMP
    }
    __syncthreads();
    for (int it = 0; it < 10; ++it) {
      if (tid < 20) {
        float m = -1e30f;
        for (int c = 0; c < 20; ++c) m = fmaxf(m, laS[tid * 20 + c]);
        float s = 0.f;
        for (int c = 0; c < 20; ++c) s += expf(laS[tid * 20 + c] - m);
        float l = m + logf(s);
        for (int c = 0; c < 20; ++c) laS[tid * 20 + c] -= l;
      }
      __syncthreads();
      if (tid < 20) {
        float m = -1e30f;
        for (int q = 0; q < 20; ++q) m = fmaxf(m, laS[q * 20 + tid]);
        float s = 0.f;
        for (int q = 0; q < 20; ++q) s += expf(laS[q * 20 + tid] - m);
        float l = m + logf(s);
        for (int q = 0; q < 20; ++q) laS[q * 20 + tid] -= l;
      }
      __syncthreads();
    }
    for (int i = tid; i < 400; i += 512) laS[i] = expf(laS[i]);
    __syncthreads();
    if (t < NT - 1) {
      // mix -> mixg; fill stgS for next-t p=2 (act half = blk block1, mix half = mixed1)
      {
        int f = tid;
        if (f < 512) {
          float oq[18], oc[18];
          short rq[18], rc[18];
          for (int j = 0; j < 18; ++j) {
            rq[j] = P.blkg[(nb + j) * 640 + f];
            rc[j] = P.blkg[(nb + 18 + j) * 640 + f];
            oq[j] = bf2f(rq[j]); oc[j] = bf2f(rc[j]);
          }
          for (int j = 0; j < 18; ++j) {
            float aq = 0.f, ac = 0.f;
            for (int k = 0; k < 18; ++k) {
              aq += laS[j * 20 + k] * oc[k];
              ac += laS[k * 20 + j] * oq[k];
            }
            short hq = f2bf(aq), hc = f2bf(ac);
            P.mixg[(nb + j) * 512 + f]      = hq;
            P.mixg[(nb + 18 + j) * 512 + f] = hc;
            if (f < 128) {
              stgS[hs_idx(j, f)]            = rq[j];
              stgS[hs_idx(18 + j, f)]       = rc[j];
              stgS[hs_idx(j, 128 + f)]      = hq;
              stgS[hs_idx(18 + j, 128 + f)] = hc;
            }
          }
        }
      }
      __syncthreads();
    } else {
      if (tid == 0) redS[0] = 0.f;
      __syncthreads();
      float sl = 0.f;
      for (int i = tid; i < 320; i += 512) {
        int q = i / 16, tt = i & 15;
        float d = 0.f;
        for (int c = 0; c < 20; ++c) d += laS[q * 20 + c] * mcS[c * 16 + tt];
        float r = mqS[i] - d;
        if (r > 0.f) sl += r;
      }
      if (sl != 0.f) atomicAdd(redS, sl);
      __syncthreads();
      if (tid == 0) P.out[b] = -redS[0];
    }
  }  // t loop
}

// W[K][N] fp32 -> WT[N][K] bf16
__global__ __launch_bounds__(256) void wtrans(const float* W, short* WT, int K, int N) {
  int i = blockIdx.x * 256 + threadIdx.x;
  if (i < K * N) {
    int n = i / K, k = i - n * K;
    WT[i] = f2bf(W[(long)k * N + n]);
  }
}

__global__ __launch_bounds__(256) void consts_kernel(
    const float* W_ne, const float* b_ne, const float* W_c1,
    const float* W_ee, const float* b_ee, const float* W_m1,
    float* c_n, float* d_n, float* c_e, float* d_e) {
  int h = threadIdx.x;
  float cn = 0.f, dn = 0.f, ce = 0.f, de = 0.f;
  for (int d = 0; d < 128; ++d) {
    float wc = W_c1[d * 256 + h];
    cn += W_ne[d] * wc; dn += b_ne[d] * wc;
    float wmv = W_m1[(256 + d) * 256 + h];
    ce += W_ee[d] * wmv; de += b_ee[d] * wmv;
  }
  c_n[h] = cn; d_n[h] = dn; c_e[h] = ce; d_e[h] = de;
}

extern "C" void kernel_launch(void* const* d_in, const int* in_sizes, int n_in,
                              void* d_out, int out_size, void* d_ws, size_t ws_size,
                              hipStream_t stream) {
  (void)in_sizes; (void)n_in; (void)out_size; (void)ws_size;
  const float* node_f = (const float*)d_in[0];
  const float* edge_f = (const float*)d_in[1];
  const float* W_ne   = (const float*)d_in[3];
  const float* b_ne   = (const float*)d_in[4];
  const float* W_ee   = (const float*)d_in[5];
  const float* b_ee   = (const float*)d_in[6];
  const float* W_m1   = (const float*)d_in[7];
  const float* b_m1   = (const float*)d_in[8];
  const float* W_m2   = (const float*)d_in[9];
  const float* b_m2   = (const float*)d_in[10];
  const float* W_u1   = (const float*)d_in[11];
  const float* b_u1   = (const float*)d_in[12];
  const float* W_u2   = (const float*)d_in[13];
  const float* b_u2   = (const float*)d_in[14];
  const float* W_c1   = (const float*)d_in[15];
  const float* b_c1   = (const float*)d_in[16];
  const float* W_c2   = (const float*)d_in[17];
  const float* b_c2   = (const float*)d_in[18];
  const float* W_t1   = (const float*)d_in[19];
  const float* b_t1   = (const float*)d_in[20];
  const float* W_t2   = (const float*)d_in[21];
  const float* b_t2   = (const float*)d_in[22];
  const int* from_idx = (const int*)d_in[23];
  const int* to_idx   = (const int*)d_in[24];

  char* base = (char*)d_ws;
  size_t off = 0;
  auto alloc = [&](size_t bytes) { char* pp = base + off; off += (bytes + 255) & ~(size_t)255; return pp; };
  short* blkg = (short*)alloc((size_t)NN * 640 * 2);
  short* mixg = (short*)alloc((size_t)NN * 512 * 2);
  short* WTc1 = (short*)alloc(256 * 256 * 2);
  short* WTm1 = (short*)alloc(256 * 256 * 2);
  short* WTu1 = (short*)alloc(256 * 256 * 2);
  short* WTc2 = (short*)alloc(128 * 256 * 2);
  short* WTm2 = (short*)alloc(128 * 256 * 2);
  short* WTu2 = (short*)alloc(128 * 256 * 2);
  float* c_n  = (float*)alloc(256 * 4);
  float* d_n  = (float*)alloc(256 * 4);
  float* c_e  = (float*)alloc(256 * 4);
  float* d_e  = (float*)alloc(256 * 4);

  wtrans<<<256, 256, 0, stream>>>(W_c1, WTc1, 256, 256);
  wtrans<<<256, 256, 0, stream>>>(W_m1, WTm1, 256, 256);  // first 256 K-rows (rest folded)
  wtrans<<<256, 256, 0, stream>>>(W_u1, WTu1, 256, 256);
  wtrans<<<128, 256, 0, stream>>>(W_c2, WTc2, 256, 128);
  wtrans<<<128, 256, 0, stream>>>(W_m2, WTm2, 256, 128);
  wtrans<<<128, 256, 0, stream>>>(W_u2, WTu2, 256, 128);
  consts_kernel<<<1, 256, 0, stream>>>(W_ne, b_ne, W_c1, W_ee, b_ee, W_m1, c_n, d_n, c_e, d_e);
  hipMemsetAsync(mixg, 0, (size_t)NN * 512 * 2, stream);

  MP mp{};
  mp.node_f = node_f; mp.edge_f = edge_f;
  mp.from_idx = from_idx; mp.to_idx = to_idx;
  mp.WTc1 = WTc1; mp.WTm1 = WTm1; mp.WTu1 = WTu1;
  mp.WTc2 = WTc2; mp.WTm2 = WTm2; mp.WTu2 = WTu2;
  mp.b_c1 = b_c1; mp.b_c2 = b_c2; mp.b_m1 = b_m1; mp.b_m2 = b_m2;
  mp.b_u1 = b_u1; mp.b_u2 = b_u2;
  mp.c_n = c_n; mp.d_n = d_n; mp.c_e = c_e; mp.d_e = d_e;
  mp.W_t1 = W_t1; mp.b_t1 = b_t1; mp.W_t2 = W_t2; mp.b_t2 = b_t2;
  mp.blkg = blkg; mp.mixg = mixg; mp.out = (float*)d_out;

  mega<<<Bq, 512, 0, stream>>>(mp);
}

// Round 17
// 2329.347 us; speedup vs baseline: 1.0164x; 1.0164x over previous
//
#include <hip/hip_runtime.h>

#define Bq   1024
#define NQS  15
#define NCS  18
#define NMSS 20
#define NN   36864
#define DD   128
#define NTD  16
#define NP   5
#define NT   3

typedef __attribute__((ext_vector_type(8))) short short8;
typedef __attribute__((ext_vector_type(4))) short short4v;
typedef __attribute__((ext_vector_type(4))) float float4v;

__device__ __forceinline__ short f2bf(float f) {
  unsigned u = __builtin_bit_cast(unsigned, f);
  u = u + 0x7FFFu + ((u >> 16) & 1u);
  return (short)(u >> 16);
}
__device__ __forceinline__ float bf2f(short s) {
  unsigned u = ((unsigned)(unsigned short)s) << 16;
  return __builtin_bit_cast(float, u);
}

// HS / stgS: stride 256 shorts + XOR swizzle
__device__ __forceinline__ int hs_idx(int row, int col) {
  return (row << 8) + ((((col >> 3) ^ (row & 7)) << 3) | (col & 7));
}
// aggS: stride 128 + XOR swizzle
__device__ __forceinline__ int ag_idx(int row, int col) {
  return (row << 7) + ((((col >> 3) ^ (row & 7)) << 3) | (col & 7));
}
// actS: stride 136, unswizzled
#define ACT_STRIDE 136
__device__ __forceinline__ int as_idx(int row, int col) {
  return row * ACT_STRIDE + col;
}
// msgS: [128 feat][72 edge-slots]
#define MS_STRIDE 72
__device__ __forceinline__ int ms_idx(int f, int e) { return f * MS_STRIDE + e; }

// LDS layout (63552 B -> 2 blocks/CU)
#define OFF_ACT 24576
#define OFF_AGG 34368
#define OFF_UNI 43584
#define OFF_FR  62016
#define OFF_TO  62528
#define OFF_EF  63040
// t-phase overlays inside HS region:
#define TO_WT1  0
#define TO_WT2  8192
#define TO_MQ   9216
#define TO_MC   10496
#define TO_LA   11776
#define TO_RED  13376
#define TO_H1   13392

struct MP {
  const float* node_f; const float* edge_f;
  const int* from_idx; const int* to_idx;
  const short *WTc1, *WTm1, *WTu1, *WTc2, *WTm2, *WTu2;  // [M][256] bf16
  const float *b_c1, *b_c2, *b_m1, *b_m2, *b_u1, *b_u2;
  const float *c_n, *d_n, *c_e, *d_e;                     // folded fp32 constants [256]
  const float *W_t1, *b_t1, *W_t2, *b_t2;
  short* blkg;   // [NN][640] bf16
  short* mixg;   // [NN][512] bf16
  float* out;
};

// K=256 GEMM, 3 n-tiles (48 cols), HALF-preload of A (4 k-steps at a time).
// Register-file math (R13 vs R16): 2 blocks/CU co-reside at VGPR=64, not at
// VGPR=128 -> pool boundary < 128. Halving the A preload (64->32 regs) drops
// total demand to ~100, letting 2 blocks (16 waves) fit.
template<int MT, typename F>
__device__ __forceinline__ void gemm3(const short* __restrict__ WT, F loadB,
                                      int wm, int quad, int l16, float4v (&acc)[MT][3]) {
  short8 afr[MT][4];
#pragma unroll
  for (int ks = 0; ks < 4; ++ks)
#pragma unroll
    for (int mt = 0; mt < MT; ++mt)
      afr[mt][ks] = *(const short8*)(WT + (long)(wm * (MT * 16) + mt * 16 + l16) * 256
                                        + ks * 32 + quad * 8);
#pragma unroll
  for (int mt = 0; mt < MT; ++mt)
#pragma unroll
    for (int nt = 0; nt < 3; ++nt) acc[mt][nt] = (float4v)0.f;
#pragma unroll
  for (int ks = 0; ks < 4; ++ks) {
    const int k0q = ks * 32 + quad * 8;
    short8 bfr[3];
#pragma unroll
    for (int nt = 0; nt < 3; ++nt) bfr[nt] = loadB(nt, k0q);
#pragma unroll
    for (int mt = 0; mt < MT; ++mt)
#pragma unroll
      for (int nt = 0; nt < 3; ++nt)
        acc[mt][nt] = __builtin_amdgcn_mfma_f32_16x16x32_bf16(afr[mt][ks], bfr[nt], acc[mt][nt], 0, 0, 0);
  }
#pragma unroll
  for (int ks = 0; ks < 4; ++ks)
#pragma unroll
    for (int mt = 0; mt < MT; ++mt)
      afr[mt][ks] = *(const short8*)(WT + (long)(wm * (MT * 16) + mt * 16 + l16) * 256
                                        + (ks + 4) * 32 + quad * 8);
#pragma unroll
  for (int ks = 4; ks < 8; ++ks) {
    const int k0q = ks * 32 + quad * 8;
    short8 bfr[3];
#pragma unroll
    for (int nt = 0; nt < 3; ++nt) bfr[nt] = loadB(nt, k0q);
#pragma unroll
    for (int mt = 0; mt < MT; ++mt)
#pragma unroll
      for (int nt = 0; nt < 3; ++nt)
        acc[mt][nt] = __builtin_amdgcn_mfma_f32_16x16x32_bf16(afr[mt][ks - 4], bfr[nt], acc[mt][nt], 0, 0, 0);
  }
}

// 1 batch / block, 512 threads, 64KB LDS, reduced reg demand -> 2 blocks/CU.
__global__ __launch_bounds__(512)
void mega(MP P) {
  __shared__ __attribute__((aligned(16))) char smem[63552];
  short* HS   = (short*)smem;               // [48][256] bf16
  short* actS = (short*)(smem + OFF_ACT);
  short* aggS = (short*)(smem + OFF_AGG);
  short* stgS = (short*)(smem + OFF_UNI);   // staged comb-B [36][256]
  short* msgS = stgS;                       // [128][72] (aliased)
  float* xsT  = (float*)(smem + OFF_UNI);   // [33][132] fp32 (aliased, p==5/t-phase)
  int*   frS  = (int*)(smem + OFF_FR);
  int*   toS  = (int*)(smem + OFF_TO);
  float* efS  = (float*)(smem + OFF_EF);
  float* wt1S = (float*)(smem + TO_WT1);
  float* wt2S = (float*)(smem + TO_WT2);
  float* mqS  = (float*)(smem + TO_MQ);
  float* mcS  = (float*)(smem + TO_MC);
  float* laS  = (float*)(smem + TO_LA);
  float* redS = (float*)(smem + TO_RED);
  float* h1S  = (float*)(smem + TO_H1);

  const int tid = threadIdx.x, lane = tid & 63, wm = tid >> 6;  // wm 0..7
  const int quad = lane >> 4, l16 = lane & 15;
  const int b = blockIdx.x;           // batch
  const long nb = (long)b * 36;

  // edge topology (t-invariant): 90 active edges, padded to 128 with to=-1
  for (int j = tid; j < 128; j += 512) {
    if (j < 90) {
      int e = b * 135 + j;
      frS[j] = P.from_idx[e] - (int)nb;
      toS[j] = P.to_idx[e] - (int)nb;
      efS[j] = P.edge_f[e];
    } else { frS[j] = 0; toS[j] = -1; efS[j] = 0.f; }
  }
  __syncthreads();

  for (int t = 0; t < NT; ++t) {
    for (int p_ = (t == 0 ? 1 : 2); p_ <= NP; ++p_) {
      // ========== comb L1 -> HS ==========
      if (p_ == 1) {
        for (int i = tid; i < 48 * 256; i += 512) {
          int node = i >> 8, h = i & 255;
          int nc = node < 36 ? node : 35;
          float nf = P.node_f[nb + nc];
          float v = nf * P.c_n[h] + P.d_n[h] + P.b_c1[h];
          HS[hs_idx(node, h)] = f2bf(v > 0.f ? v : 0.f);
        }
      } else {
        float4v acc[2][3];
        gemm3<2>(P.WTc1, [&](int nt, int k0q) -> short8 {
          int n = nt * 16 + l16; int nc = n < 36 ? n : 35;
          return *(const short8*)(&stgS[hs_idx(nc, k0q)]);
        }, wm, quad, l16, acc);
#pragma unroll
        for (int mt = 0; mt < 2; ++mt) {
          const int h0 = wm * 32 + mt * 16 + quad * 4;
          float4v bv = *(const float4v*)(P.b_c1 + h0);
#pragma unroll
          for (int nt = 0; nt < 3; ++nt) {
            const int col = nt * 16 + l16;
            short4v hv;
#pragma unroll
            for (int r = 0; r < 4; ++r) {
              float v = acc[mt][nt][r] + bv[r];
              hv[r] = f2bf(v > 0.f ? v : 0.f);
            }
            *(short4v*)(&HS[hs_idx(col, h0)]) = hv;
          }
        }
      }
      __syncthreads();
      // ========== comb L2 -> actS ==========
      {
        float4v acc2[1][3];
        gemm3<1>(P.WTc2, [&](int nt, int k0q) -> short8 {
          return *(const short8*)(&HS[hs_idx(nt * 16 + l16, k0q)]);
        }, wm, quad, l16, acc2);
        const int f0 = wm * 16 + quad * 4;
        float4v bv = *(const float4v*)(P.b_c2 + f0);
#pragma unroll
        for (int nt = 0; nt < 3; ++nt) {
          int node = nt * 16 + l16;
          if (node < 36) {
            short4v ov;
#pragma unroll
            for (int r = 0; r < 4; ++r) ov[r] = f2bf(acc2[0][nt][r] + bv[r]);
            *(short4v*)(&actS[as_idx(node, f0)]) = ov;
          }
        }
      }
      __syncthreads();
      // ========== msg: 2 chunks of 48 edges ==========
      for (int c2 = 0; c2 < 2; ++c2) {
        // msg L1 -> HS
        {
          int fa[3], ta[3]; float ev[3];
#pragma unroll
          for (int nt = 0; nt < 3; ++nt) {
            int j = c2 * 48 + nt * 16 + l16;
            int fv = frS[j]; fa[nt] = fv < 0 ? 0 : fv;
            int tv = toS[j]; ta[nt] = tv < 0 ? 0 : tv;
            ev[nt] = efS[j];
          }
          float4v acc[2][3];
          gemm3<2>(P.WTm1, [&](int nt, int k0q) -> short8 {
            return (k0q < 128) ? *(const short8*)(&actS[as_idx(fa[nt], k0q)])
                               : *(const short8*)(&actS[as_idx(ta[nt], k0q - 128)]);
          }, wm, quad, l16, acc);
#pragma unroll
          for (int mt = 0; mt < 2; ++mt) {
            const int h0 = wm * 32 + mt * 16 + quad * 4;
            float4v bv = *(const float4v*)(P.b_m1 + h0);
            float4v ce = *(const float4v*)(P.c_e + h0);
            float4v de = *(const float4v*)(P.d_e + h0);
#pragma unroll
            for (int nt = 0; nt < 3; ++nt) {
              const int col = nt * 16 + l16;
              short4v hv;
#pragma unroll
              for (int r = 0; r < 4; ++r) {
                float v = acc[mt][nt][r] + bv[r] + de[r] + ev[nt] * ce[r];
                hv[r] = f2bf(v > 0.f ? v : 0.f);
              }
              *(short4v*)(&HS[hs_idx(col, h0)]) = hv;
            }
          }
        }
        __syncthreads();
        // msg L2 -> msgS
        {
          float4v acc2[1][3];
          gemm3<1>(P.WTm2, [&](int nt, int k0q) -> short8 {
            return *(const short8*)(&HS[hs_idx(nt * 16 + l16, k0q)]);
          }, wm, quad, l16, acc2);
          const int f0 = wm * 16 + quad * 4;
          float4v bv = *(const float4v*)(P.b_m2 + f0);
#pragma unroll
          for (int nt = 0; nt < 3; ++nt) {
            int e = nt * 16 + l16;
#pragma unroll
            for (int r = 0; r < 4; ++r)
              msgS[ms_idx(f0 + r, e)] = f2bf(acc2[0][nt][r] + bv[r]);
          }
        }
        __syncthreads();
        // agg chunk c2: aggS[node][f] (+)= Adj-select over 48 edges (K padded to 64)
        {
          float4v ag[3];
#pragma unroll
          for (int nt = 0; nt < 3; ++nt) ag[nt] = (float4v)0.f;
          const short ONE = (short)0x3F80;
#pragma unroll
          for (int ks = 0; ks < 2; ++ks) {
            const int k0 = ks * 32 + quad * 8;
            short8 a0 = *(const short8*)(&msgS[ms_idx(wm * 16 + l16, k0)]);
            int tv[8];
#pragma unroll
            for (int j = 0; j < 8; ++j) {
              int kk = k0 + j;
              tv[j] = (kk < 48) ? toS[c2 * 48 + kk] : -1;  // mask pad slots 48..63
            }
#pragma unroll
            for (int nt = 0; nt < 3; ++nt) {
              const int node = nt * 16 + l16;
              short8 bfr;
#pragma unroll
              for (int j = 0; j < 8; ++j) bfr[j] = (tv[j] == node) ? ONE : (short)0;
              ag[nt] = __builtin_amdgcn_mfma_f32_16x16x32_bf16(a0, bfr, ag[nt], 0, 0, 0);
            }
          }
          const int f0 = wm * 16 + quad * 4;
#pragma unroll
          for (int nt = 0; nt < 3; ++nt) {
            int node = nt * 16 + l16;
            if (node < 36) {
              if (c2 == 0) {
                short4v o2;
#pragma unroll
                for (int r = 0; r < 4; ++r) o2[r] = f2bf(ag[nt][r]);
                *(short4v*)(&aggS[ag_idx(node, f0)]) = o2;
              } else {
                short4v prev = *(short4v*)(&aggS[ag_idx(node, f0)]);
                short4v o2;
#pragma unroll
                for (int r = 0; r < 4; ++r) o2[r] = f2bf(bf2f(prev[r]) + ag[nt][r]);
                *(short4v*)(&aggS[ag_idx(node, f0)]) = o2;
              }
            }
          }
        }
        __syncthreads();
      }
      // ========== upd L1 -> HS (+ stage mixg half for next p) ==========
      {
        if (p_ < 5) {
          for (int i = tid; i < 36 * 16; i += 512) {
            int row = i >> 4, col = (i & 15) << 3;
            short8 v = *(const short8*)(P.mixg + (nb + row) * 512 + (p_ - 1) * 128 + col);
            *(short8*)(&stgS[hs_idx(row, 128 + col)]) = v;
          }
        }
        float4v acc[2][3];
        gemm3<2>(P.WTu1, [&](int nt, int k0q) -> short8 {
          int n = nt * 16 + l16; int nc = n < 36 ? n : 35;
          return (k0q < 128) ? *(const short8*)(&actS[as_idx(nc, k0q)])
                             : *(const short8*)(&aggS[ag_idx(nc, k0q - 128)]);
        }, wm, quad, l16, acc);
#pragma unroll
        for (int mt = 0; mt < 2; ++mt) {
          const int h0 = wm * 32 + mt * 16 + quad * 4;
          float4v bv = *(const float4v*)(P.b_u1 + h0);
#pragma unroll
          for (int nt = 0; nt < 3; ++nt) {
            const int col = nt * 16 + l16;
            short4v hv;
#pragma unroll
            for (int r = 0; r < 4; ++r) {
              float v = acc[mt][nt][r] + bv[r];
              hv[r] = f2bf(v > 0.f ? v : 0.f);
            }
            *(short4v*)(&HS[hs_idx(col, h0)]) = hv;
          }
        }
      }
      __syncthreads();
      // ========== upd L2 -> blkg(NT)+stgS (p<5) or xsT fp32 (p==5) ==========
      {
        float4v acc2[1][3];
        gemm3<1>(P.WTu2, [&](int nt, int k0q) -> short8 {
          return *(const short8*)(&HS[hs_idx(nt * 16 + l16, k0q)]);
        }, wm, quad, l16, acc2);
        const int f0 = wm * 16 + quad * 4;
        float4v bv = *(const float4v*)(P.b_u2 + f0);
#pragma unroll
        for (int nt = 0; nt < 3; ++nt) {
          int node = nt * 16 + l16;
          if (node < 36) {
            if (p_ < 5) {
              short4v ov;
#pragma unroll
              for (int r = 0; r < 4; ++r) ov[r] = f2bf(acc2[0][nt][r] + bv[r]);
              __builtin_nontemporal_store(ov, (short4v*)(P.blkg + (nb + node) * 640 + (p_ - 1) * 128 + f0));
              *(short4v*)(&stgS[hs_idx(node, f0)]) = ov;
            } else {
              if (node < 15 || node >= 18) {
                int row = (node < 15) ? node : node - 3;
                float4v xv;
#pragma unroll
                for (int r = 0; r < 4; ++r) xv[r] = acc2[0][nt][r] + bv[r];
                *(float4v*)(&xsT[row * 132 + f0]) = xv;
              }
            }
          }
        }
      }
      __syncthreads();
    }  // p loop

    // ================= t-phase (1 batch) =================
    for (int i = tid; i < 2048; i += 512) wt1S[i] = P.W_t1[i];
    if (tid < 256) wt2S[tid] = P.W_t2[tid];
    for (int i = tid; i < NMSS * NTD; i += 512) {
      int r = i >> 4;
      if (r >= NQS) mqS[i] = 0.f;
      if (r >= NCS) mcS[i] = 0.f;
    }
    __syncthreads();
    for (int i = tid; i < 33 * NTD; i += 512) {
      int r = i / NTD, c = i % NTD;
      float s = P.b_t1[c];
      for (int k = 0; k < 128; ++k) s += xsT[r * 132 + k] * wt1S[k * NTD + c];
      h1S[i] = s > 0.f ? s : 0.f;
    }
    __syncthreads();
    for (int i = tid; i < 33 * NTD; i += 512) {
      int r = i / NTD, c = i % NTD;
      float s = P.b_t2[c];
      for (int k = 0; k < NTD; ++k) s += h1S[r * NTD + k] * wt2S[k * NTD + c];
      if (r < NQS) mqS[r * NTD + c] = s;
      else         mcS[(r - NQS) * NTD + c] = s;
    }
    __syncthreads();
    for (int i = tid; i < 400; i += 512) {
      int q = i / 20, c = i - q * 20;
      float s = 0.f;
      for (int k = 0; k < NTD; ++k) s += mqS[q * NTD + k] * mcS[c * NTD + k];
      laS[i] = s * 10.f;  // / SINKHORN_TEMP
    }
    __syncthreads();
    for (int it = 0; it < 10; ++it) {
      if (tid < 20) {
        float m = -1e30f;
        for (int c = 0; c < 20; ++c) m = fmaxf(m, laS[tid * 20 + c]);
        float s = 0.f;
        for (int c = 0; c < 20; ++c) s += expf(laS[tid * 20 + c] - m);
        float l = m + logf(s);
        for (int c = 0; c < 20; ++c) laS[tid * 20 + c] -= l;
      }
      __syncthreads();
      if (tid < 20) {
        float m = -1e30f;
        for (int q = 0; q < 20; ++q) m = fmaxf(m, laS[q * 20 + tid]);
        float s = 0.f;
        for (int q = 0; q < 20; ++q) s += expf(laS[q * 20 + tid] - m);
        float l = m + logf(s);
        for (int q = 0; q < 20; ++q) laS[q * 20 + tid] -= l;
      }
      __syncthreads();
    }
    for (int i = tid; i < 400; i += 512) laS[i] = expf(laS[i]);
    __syncthreads();
    if (t < NT - 1) {
      // mix -> mixg; fill stgS for next-t p=2 (act half = blk block1, mix half = mixed1)
      {
        int f = tid;
        if (f < 512) {
          float oq[18], oc[18];
          short rq[18], rc[18];
          for (int j = 0; j < 18; ++j) {
            rq[j] = P.blkg[(nb + j) * 640 + f];
            rc[j] = P.blkg[(nb + 18 + j) * 640 + f];
            oq[j] = bf2f(rq[j]); oc[j] = bf2f(rc[j]);
          }
          for (int j = 0; j < 18; ++j) {
            float aq = 0.f, ac = 0.f;
            for (int k = 0; k < 18; ++k) {
              aq += laS[j * 20 + k] * oc[k];
              ac += laS[k * 20 + j] * oq[k];
            }
            short hq = f2bf(aq), hc = f2bf(ac);
            P.mixg[(nb + j) * 512 + f]      = hq;
            P.mixg[(nb + 18 + j) * 512 + f] = hc;
            if (f < 128) {
              stgS[hs_idx(j, f)]            = rq[j];
              stgS[hs_idx(18 + j, f)]       = rc[j];
              stgS[hs_idx(j, 128 + f)]      = hq;
              stgS[hs_idx(18 + j, 128 + f)] = hc;
            }
          }
        }
      }
      __syncthreads();
    } else {
      if (tid == 0) redS[0] = 0.f;
      __syncthreads();
      float sl = 0.f;
      for (int i = tid; i < 320; i += 512) {
        int q = i / 16, tt = i & 15;
        float d = 0.f;
        for (int c = 0; c < 20; ++c) d += laS[q * 20 + c] * mcS[c * 16 + tt];
        float r = mqS[i] - d;
        if (r > 0.f) sl += r;
      }
      if (sl != 0.f) atomicAdd(redS, sl);
      __syncthreads();
      if (tid == 0) P.out[b] = -redS[0];
    }
  }  // t loop
}

// W[K][N] fp32 -> WT[N][K] bf16
__global__ __launch_bounds__(256) void wtrans(const float* W, short* WT, int K, int N) {
  int i = blockIdx.x * 256 + threadIdx.x;
  if (i < K * N) {
    int n = i / K, k = i - n * K;
    WT[i] = f2bf(W[(long)k * N + n]);
  }
}

__global__ __launch_bounds__(256) void consts_kernel(
    const float* W_ne, const float* b_ne, const float* W_c1,
    const float* W_ee, const float* b_ee, const float* W_m1,
    float* c_n, float* d_n, float* c_e, float* d_e) {
  int h = threadIdx.x;
  float cn = 0.f, dn = 0.f, ce = 0.f, de = 0.f;
  for (int d = 0; d < 128; ++d) {
    float wc = W_c1[d * 256 + h];
    cn += W_ne[d] * wc; dn += b_ne[d] * wc;
    float wmv = W_m1[(256 + d) * 256 + h];
    ce += W_ee[d] * wmv; de += b_ee[d] * wmv;
  }
  c_n[h] = cn; d_n[h] = dn; c_e[h] = ce; d_e[h] = de;
}

extern "C" void kernel_launch(void* const* d_in, const int* in_sizes, int n_in,
                              void* d_out, int out_size, void* d_ws, size_t ws_size,
                              hipStream_t stream) {
  (void)in_sizes; (void)n_in; (void)out_size; (void)ws_size;
  const float* node_f = (const float*)d_in[0];
  const float* edge_f = (const float*)d_in[1];
  const float* W_ne   = (const float*)d_in[3];
  const float* b_ne   = (const float*)d_in[4];
  const float* W_ee   = (const float*)d_in[5];
  const float* b_ee   = (const float*)d_in[6];
  const float* W_m1   = (const float*)d_in[7];
  const float* b_m1   = (const float*)d_in[8];
  const float* W_m2   = (const float*)d_in[9];
  const float* b_m2   = (const float*)d_in[10];
  const float* W_u1   = (const float*)d_in[11];
  const float* b_u1   = (const float*)d_in[12];
  const float* W_u2   = (const float*)d_in[13];
  const float* b_u2   = (const float*)d_in[14];
  const float* W_c1   = (const float*)d_in[15];
  const float* b_c1   = (const float*)d_in[16];
  const float* W_c2   = (const float*)d_in[17];
  const float* b_c2   = (const float*)d_in[18];
  const float* W_t1   = (const float*)d_in[19];
  const float* b_t1   = (const float*)d_in[20];
  const float* W_t2   = (const float*)d_in[21];
  const float* b_t2   = (const float*)d_in[22];
  const int* from_idx = (const int*)d_in[23];
  const int* to_idx   = (const int*)d_in[24];

  char* base = (char*)d_ws;
  size_t off = 0;
  auto alloc = [&](size_t bytes) { char* pp = base + off; off += (bytes + 255) & ~(size_t)255; return pp; };
  short* blkg = (short*)alloc((size_t)NN * 640 * 2);
  short* mixg = (short*)alloc((size_t)NN * 512 * 2);
  short* WTc1 = (short*)alloc(256 * 256 * 2);
  short* WTm1 = (short*)alloc(256 * 256 * 2);
  short* WTu1 = (short*)alloc(256 * 256 * 2);
  short* WTc2 = (short*)alloc(128 * 256 * 2);
  short* WTm2 = (short*)alloc(128 * 256 * 2);
  short* WTu2 = (short*)alloc(128 * 256 * 2);
  float* c_n  = (float*)alloc(256 * 4);
  float* d_n  = (float*)alloc(256 * 4);
  float* c_e  = (float*)alloc(256 * 4);
  float* d_e  = (float*)alloc(256 * 4);

  wtrans<<<256, 256, 0, stream>>>(W_c1, WTc1, 256, 256);
  wtrans<<<256, 256, 0, stream>>>(W_m1, WTm1, 256, 256);  // first 256 K-rows (rest folded)
  wtrans<<<256, 256, 0, stream>>>(W_u1, WTu1, 256, 256);
  wtrans<<<128, 256, 0, stream>>>(W_c2, WTc2, 256, 128);
  wtrans<<<128, 256, 0, stream>>>(W_m2, WTm2, 256, 128);
  wtrans<<<128, 256, 0, stream>>>(W_u2, WTu2, 256, 128);
  consts_kernel<<<1, 256, 0, stream>>>(W_ne, b_ne, W_c1, W_ee, b_ee, W_m1, c_n, d_n, c_e, d_e);
  hipMemsetAsync(mixg, 0, (size_t)NN * 512 * 2, stream);

  MP mp{};
  mp.node_f = node_f; mp.edge_f = edge_f;
  mp.from_idx = from_idx; mp.to_idx = to_idx;
  mp.WTc1 = WTc1; mp.WTm1 = WTm1; mp.WTu1 = WTu1;
  mp.WTc2 = WTc2; mp.WTm2 = WTm2; mp.WTu2 = WTu2;
  mp.b_c1 = b_c1; mp.b_c2 = b_c2; mp.b_m1 = b_m1; mp.b_m2 = b_m2;
  mp.b_u1 = b_u1; mp.b_u2 = b_u2;
  mp.c_n = c_n; mp.d_n = d_n; mp.c_e = c_e; mp.d_e = d_e;
  mp.W_t1 = W_t1; mp.b_t1 = b_t1; mp.W_t2 = W_t2; mp.b_t2 = b_t2;
  mp.blkg = blkg; mp.mixg = mixg; mp.out = (float*)d_out;

  mega<<<Bq, 512, 0, stream>>>(mp);
}